// Round 9
// baseline (5394.431 us; speedup 1.0000x reference)
//
#include <hip/hip_runtime.h>
#include <hip/hip_fp16.h>
#include <math.h>

#define BATCH 32
#define TLEN  1024
#define DIN   128
#define HID   512
#define NCLS  10
#define SENT64 0xFFFFFFFFFFFFFFFFull
#define POLL_CAP (1u<<17)
#define PADR 68          // padded K-region stride in u32 words (64 + 4)

typedef _Float16 hf2 __attribute__((ext_vector_type(2)));

__device__ __forceinline__ unsigned long long aload64(const unsigned long long* p) {
  return __hip_atomic_load(p, __ATOMIC_RELAXED, __HIP_MEMORY_SCOPE_AGENT);
}
__device__ __forceinline__ void astore64(unsigned long long* p, unsigned long long v) {
  __hip_atomic_store(p, v, __ATOMIC_RELAXED, __HIP_MEMORY_SCOPE_AGENT);
}

__device__ __forceinline__ float fdot2u(unsigned a, unsigned b, float c) {
#if __has_builtin(__builtin_amdgcn_fdot2)
  return __builtin_amdgcn_fdot2(__builtin_bit_cast(hf2, a),
                                __builtin_bit_cast(hf2, b), c, false);
#else
  hf2 av = __builtin_bit_cast(hf2, a), bv = __builtin_bit_cast(hf2, b);
  return c + (float)av[0] * (float)bv[0] + (float)av[1] * (float)bv[1];
#endif
}
__device__ __forceinline__ unsigned packh2(float lo, float hi) {
  __half2 h = __floats2half2_rn(lo, hi);
  return __builtin_bit_cast(unsigned, h);
}
__device__ __forceinline__ float f16of(unsigned u, int hi) {
  hf2 v = __builtin_bit_cast(hf2, u);
  return (float)v[hi];
}

// ---------- prep: pack the streamed col (col3 of each 4-col thread block) ----
// wcol3[role][chunk i=0..15][tid=0..511] : uint4 = weight words 4i..4i+3
__global__ __launch_bounds__(512) void k_prep(
    const float* __restrict__ Wh1, const float* __restrict__ Wx2,
    const float* __restrict__ Wh2, uint4* __restrict__ wcol3)
{
  const int r = blockIdx.x >> 4;
  const int i = blockIdx.x & 15;
  const int tid = threadIdx.x;
  const int w = tid >> 6, l = tid & 63, q = l >> 4, lo = l & 15;
  const int col3 = 4 * (w * 16 + lo) + 3;
  const int k0 = q * 128;
  const float* W = (r == 0) ? Wh1 : ((r == 1) ? Wx2 : Wh2);
  unsigned vv[4];
#pragma unroll
  for (int j = 0; j < 4; ++j) {
    const int k = k0 + 2 * (4 * i + j);
    vv[j] = packh2(W[(size_t)k * HID + col3], W[(size_t)(k + 1) * HID + col3]);
  }
  wcol3[((size_t)r * 16 + i) * 512 + tid] = make_uint4(vv[0], vv[1], vv[2], vv[3]);
}

// ---------- xw1[t,b,:] = x[b,t,:] @ Wx1 + b1, packed f16 pairs, all T ----------
__global__ __launch_bounds__(256) void k_xw1(
    const float* __restrict__ x, const float* __restrict__ Wx1,
    const float* __restrict__ b1, unsigned* __restrict__ xw1)   // [T*B][256] words
{
  __shared__ float xst[DIN * 4];
  const int tid  = threadIdx.x;
  const int row0 = blockIdx.x * 4;            // row = t*32 + b
  for (int idx = tid; idx < 4 * DIN; idx += 256) {
    int r = idx >> 7, d = idx & (DIN - 1);
    int row = row0 + r;
    int t = row >> 5, b = row & 31;
    xst[d * 4 + r] = x[((size_t)b * TLEN + t) * DIN + d];
  }
  __syncthreads();
  float acc[4][2];
#pragma unroll
  for (int r = 0; r < 4; ++r) { acc[r][0] = 0.f; acc[r][1] = 0.f; }
  const int j0 = 2 * tid, j1 = 2 * tid + 1;
  for (int d = 0; d < DIN; ++d) {
    float w0 = Wx1[(size_t)d * HID + j0];
    float w1 = Wx1[(size_t)d * HID + j1];
    float4 xv = *reinterpret_cast<const float4*>(&xst[d * 4]);
    acc[0][0] += xv.x * w0; acc[0][1] += xv.x * w1;
    acc[1][0] += xv.y * w0; acc[1][1] += xv.y * w1;
    acc[2][0] += xv.z * w0; acc[2][1] += xv.z * w1;
    acc[3][0] += xv.w * w0; acc[3][1] += xv.w * w1;
  }
  float bb0 = b1[j0], bb1 = b1[j1];
#pragma unroll
  for (int r = 0; r < 4; ++r)
    xw1[(size_t)(row0 + r) * 256 + tid] = packh2(acc[r][0] + bb0, acc[r][1] + bb1);
}

// ---------- persistent 3-role recurrence: 1 batch per WG, chains LDS-local ----
// grid 96 x 512: role = wg/32 (0=A: h1 chain, 1=B: xw2 GEMV, 2=C: h2 chain),
// b = wg%32. Thread (w,l): q=l>>4 (K-quarter, 128 rows), lo=l&15; owns 4 cols
// cb..cb+3, cb=4*(w*16+lo). Weights: cols 0-2 in VGPR (192 words), col 3
// streamed from L2 (wcol3, 8-deep pipelined). h vector in LDS, K-regions
// padded to PADR=68 words -> conflict-free b128 reads. One barrier/step.
// A->B and B->C links: sentinel-flagged full-length u64 buffers (no wrap).
__global__ __launch_bounds__(512, 2) void k_rnn(
    const unsigned* __restrict__ xw1,            // [T*B][256] f16-pair words
    const float* __restrict__ Wh1, const float* __restrict__ Wx2,
    const float* __restrict__ Wh2, const float* __restrict__ b2,
    const uint4* __restrict__ wcol3,             // [3][16][512]
    unsigned long long* __restrict__ h1f,        // [T][B][128] u64 f16x4 (sentinel-init)
    unsigned long long* __restrict__ xw2f,       // [T][B][128] u64 f16x4 (sentinel-init)
    float* __restrict__ h2fin)                   // [B][H]
{
  const int tid  = threadIdx.x;
  const int wgid = blockIdx.x;
  const int role = wgid >> 5;
  const int b    = wgid & 31;
  const int w  = tid >> 6, l = tid & 63;
  const int q  = l >> 4;
  const int lo = l & 15;
  const int cb = 4 * (w * 16 + lo);            // col base (4 cols per thread)
  const int k0 = q * 128;                      // K-row base for this quarter

  __shared__ __align__(16) unsigned h_s[2][4 * PADR];

  // zero both parities (covers pads)
  for (int idx = tid; idx < 2 * 4 * PADR; idx += 512)
    ((unsigned*)h_s)[idx] = 0u;

  // ---- load 3 cols of weights into VGPRs (one-time) ----
  const float* WS = (role == 0) ? Wh1 : ((role == 1) ? Wx2 : Wh2);
  unsigned w0[64], w1[64], w2[64];
#pragma unroll
  for (int m = 0; m < 64; ++m) {
    const int k = k0 + 2 * m;
    const float *r0 = &WS[(size_t)k * HID + cb], *r1 = &WS[(size_t)(k + 1) * HID + cb];
    w0[m] = packh2(r0[0], r1[0]);
    w1[m] = packh2(r0[1], r1[1]);
    w2[m] = packh2(r0[2], r1[2]);
  }
  const uint4* wc3 = wcol3 + (size_t)role * 16 * 512;
  float4 b2v = make_float4(0.f, 0.f, 0.f, 0.f);
  if (role == 1 && q == 0) b2v = *reinterpret_cast<const float4*>(&b2[cb]);

  // padded LDS word address for staging u64 #j (covers cols 4j..4j+3 -> words 2j,2j+1)
  // stage addr for global h word g: (g>>6)*PADR + (g&63)
  const int sgA = cb >> 1;                           // A/C self-stage word base
  const int padA = (sgA >> 6) * PADR + (sgA & 63);
  const int sgB = 2 * tid;                           // B stage (tid<128)
  const int padB = (sgB >> 6) * PADR + (sgB & 63);

  unsigned long long hu = 0;                         // my 4 outputs of prev step
  __syncthreads();

  uint4 wc[8];

  for (int t = 0; t < TLEN; ++t) {
    const int p = t & 1;
    unsigned long long xv = 0;                       // A: xw1 word; C: xw2 probe
    const unsigned long long* cprobe = nullptr;

    // ---------------- phase 1 (pre-barrier): stage + probes + wc prologue ----
    if (role == 0) {
      if (q == 0) {
        if (t > 0) *(unsigned long long*)&h_s[p][padA] = hu;   // h1(t-1) -> LDS
        xv = *(const unsigned long long*)&xw1[((size_t)t * BATCH + b) * 256 + (cb >> 1)];
      }
    } else if (role == 1) {
      const unsigned long long* ph = &h1f[((size_t)t * BATCH + b) * 128 + tid];
      unsigned long long pv = (tid < 128) ? aload64(ph) : 0;   // early probe
#pragma unroll
      for (int j = 0; j < 8; ++j) wc[j] = wc3[(size_t)j * 512 + tid];
      if (tid < 128) {
        unsigned it = 0;
        while (pv == SENT64 && ++it < POLL_CAP) pv = aload64(ph);
        if (pv == SENT64) pv = 0;
        *(unsigned long long*)&h_s[p][padB] = pv;              // h1(t) -> LDS
      }
    } else {
      if (q == 0) {
        if (t > 0) *(unsigned long long*)&h_s[p][padA] = hu;   // h2(t-1) -> LDS
        cprobe = &xw2f[((size_t)t * BATCH + b) * 128 + (w * 16 + lo)];
        xv = aload64(cprobe);                                  // early probe
      }
    }
    if (role != 1) {
#pragma unroll
      for (int j = 0; j < 8; ++j) wc[j] = wc3[(size_t)j * 512 + tid];
    }

    __syncthreads();   // h stage complete for parity p

    // ---------------- phase 2: publish prev step's output (drains next barrier)
    if (role == 0 && q == 0 && t > 0)
      astore64(&h1f[((size_t)(t - 1) * BATCH + b) * 128 + (w * 16 + lo)], hu);
    if (role == 1 && q == 0 && t > 0)
      astore64(&xw2f[((size_t)(t - 1) * BATCH + b) * 128 + (w * 16 + lo)], hu);

    // ---------------- phase 3: dot over this K-quarter, 4 cols --------------
    float a0 = 0.f, a1 = 0.f, a2 = 0.f, a3 = 0.f;
#pragma unroll
    for (int i = 0; i < 16; ++i) {
      uint4 hv = *reinterpret_cast<const uint4*>(&h_s[p][q * PADR + 4 * i]);
      uint4 cw = wc[i & 7];
      if (i < 8) wc[i & 7] = wc3[(size_t)(i + 8) * 512 + tid];   // refill pipeline
      a0 = fdot2u(hv.x, w0[4 * i + 0], a0);
      a0 = fdot2u(hv.y, w0[4 * i + 1], a0);
      a0 = fdot2u(hv.z, w0[4 * i + 2], a0);
      a0 = fdot2u(hv.w, w0[4 * i + 3], a0);
      a1 = fdot2u(hv.x, w1[4 * i + 0], a1);
      a1 = fdot2u(hv.y, w1[4 * i + 1], a1);
      a1 = fdot2u(hv.z, w1[4 * i + 2], a1);
      a1 = fdot2u(hv.w, w1[4 * i + 3], a1);
      a2 = fdot2u(hv.x, w2[4 * i + 0], a2);
      a2 = fdot2u(hv.y, w2[4 * i + 1], a2);
      a2 = fdot2u(hv.z, w2[4 * i + 2], a2);
      a2 = fdot2u(hv.w, w2[4 * i + 3], a2);
      a3 = fdot2u(hv.x, cw.x, a3);
      a3 = fdot2u(hv.y, cw.y, a3);
      a3 = fdot2u(hv.z, cw.z, a3);
      a3 = fdot2u(hv.w, cw.w, a3);
    }
    // reduce across the 4 K-quarters (lanes q*16+lo)
    a0 += __shfl_xor(a0, 16); a0 += __shfl_xor(a0, 32);
    a1 += __shfl_xor(a1, 16); a1 += __shfl_xor(a1, 32);
    a2 += __shfl_xor(a2, 16); a2 += __shfl_xor(a2, 32);
    a3 += __shfl_xor(a3, 16); a3 += __shfl_xor(a3, 32);

    // ---------------- phase 4: finalize (q0 lanes own the 4 cols) -----------
    if (q == 0) {
      if (role == 0) {
        unsigned xl = (unsigned)xv, xh = (unsigned)(xv >> 32);
        float h0v = tanhf(a0 + f16of(xl, 0));
        float h1v = tanhf(a1 + f16of(xl, 1));
        float h2v = tanhf(a2 + f16of(xh, 0));
        float h3v = tanhf(a3 + f16of(xh, 1));
        hu = ((unsigned long long)packh2(h2v, h3v) << 32) | packh2(h0v, h1v);
      } else if (role == 1) {
        hu = ((unsigned long long)packh2(a2 + b2v.z, a3 + b2v.w) << 32)
             | packh2(a0 + b2v.x, a1 + b2v.y);
      } else {
        // resolve xw2 probe (usually already hit)
        if (xv == SENT64) {
          unsigned it = 0;
          do { xv = aload64(cprobe); } while (xv == SENT64 && ++it < POLL_CAP);
          if (xv == SENT64) xv = 0;
        }
        unsigned xl = (unsigned)xv, xh = (unsigned)(xv >> 32);
        float h0v = tanhf(a0 + f16of(xl, 0));
        float h1v = tanhf(a1 + f16of(xl, 1));
        float h2v = tanhf(a2 + f16of(xh, 0));
        float h3v = tanhf(a3 + f16of(xh, 1));
        hu = ((unsigned long long)packh2(h2v, h3v) << 32) | packh2(h0v, h1v);
        if (t == TLEN - 1)
          *reinterpret_cast<float4*>(&h2fin[(size_t)b * HID + cb]) =
              make_float4(h0v, h1v, h2v, h3v);
      }
    }
  }
  // epilogue: publish the final step's output for downstream consumers
  if (role == 0 && q == 0)
    astore64(&h1f[((size_t)(TLEN - 1) * BATCH + b) * 128 + (w * 16 + lo)], hu);
  if (role == 1 && q == 0)
    astore64(&xw2f[((size_t)(TLEN - 1) * BATCH + b) * 128 + (w * 16 + lo)], hu);
}

// ---------- softmax(h2 @ Wo + bo) ----------
__global__ __launch_bounds__(640) void k_head(
    const float* __restrict__ h2, const float* __restrict__ Wo,
    const float* __restrict__ bo, float* __restrict__ out)
{
  __shared__ float lg[16];
  const int b = blockIdx.x;
  const int c = threadIdx.x >> 6;   // wave per class
  const int l = threadIdx.x & 63;
  float p = 0.f;
#pragma unroll
  for (int i = 0; i < 8; ++i) {
    int k = l + 64 * i;
    p += h2[(size_t)b * HID + k] * Wo[(size_t)k * NCLS + c];
  }
  for (int off = 32; off; off >>= 1) p += __shfl_down(p, off);
  if (l == 0) lg[c] = p + bo[c];
  __syncthreads();
  if (threadIdx.x == 0) {
    float m = lg[0];
    for (int i = 1; i < NCLS; ++i) m = fmaxf(m, lg[i]);
    float e[NCLS];
    float s = 0.f;
    for (int i = 0; i < NCLS; ++i) { e[i] = expf(lg[i] - m); s += e[i]; }
    for (int i = 0; i < NCLS; ++i) out[(size_t)b * NCLS + i] = e[i] / s;
  }
}

extern "C" void kernel_launch(void* const* d_in, const int* in_sizes, int n_in,
                              void* d_out, int out_size, void* d_ws, size_t ws_size,
                              hipStream_t stream)
{
  (void)in_sizes; (void)n_in; (void)out_size; (void)ws_size;
  const float* x   = (const float*)d_in[0];
  const float* Wx1 = (const float*)d_in[1];
  const float* Wh1 = (const float*)d_in[2];
  const float* b1  = (const float*)d_in[3];
  const float* Wx2 = (const float*)d_in[4];
  const float* Wh2 = (const float*)d_in[5];
  const float* b2  = (const float*)d_in[6];
  const float* Wo  = (const float*)d_in[7];
  const float* bo  = (const float*)d_in[8];
  float* out = (float*)d_out;

  char* ws = (char*)d_ws;
  size_t o = 0;
  unsigned* xw1 = (unsigned*)(ws + o);              o += (size_t)TLEN * BATCH * 256 * 4;  // 32MB
  unsigned long long* h1f  = (unsigned long long*)(ws + o); o += (size_t)TLEN * BATCH * 128 * 8; // 32MB
  unsigned long long* xw2f = (unsigned long long*)(ws + o); o += (size_t)TLEN * BATCH * 128 * 8; // 32MB
  uint4* wcol3 = (uint4*)(ws + o);                  o += (size_t)3 * 16 * 512 * 16;       // 384KB
  float* h2fin = (float*)(ws + o);                  o += (size_t)BATCH * HID * 4;

  // sentinel-init the two link buffers (contiguous, 64MB)
  hipMemsetAsync(h1f, 0xFF, (size_t)2 * TLEN * BATCH * 128 * 8, stream);

  k_prep<<<48, 512, 0, stream>>>(Wh1, Wx2, Wh2, wcol3);
  k_xw1<<<TLEN * BATCH / 4, 256, 0, stream>>>(x, Wx1, b1, xw1);
  k_rnn<<<96, 512, 0, stream>>>(xw1, Wh1, Wx2, Wh2, b2, wcol3, h1f, xw2f, h2fin);
  k_head<<<BATCH, 640, 0, stream>>>(h2fin, Wo, bo, out);
}

// Round 10
// 4614.377 us; speedup vs baseline: 1.1690x; 1.1690x over previous
//
#include <hip/hip_runtime.h>
#include <hip/hip_fp16.h>
#include <math.h>

#define BATCH 32
#define TLEN  1024
#define DIN   128
#define HID   512
#define NCLS  10
#define SENT64 0xFFFFFFFFFFFFFFFFull
#define POLL_CAP (1u<<17)
#define PADR 68          // padded K-region stride in u32 words (64 + 4)

typedef _Float16 hf2 __attribute__((ext_vector_type(2)));

__device__ __forceinline__ unsigned long long aload64(const unsigned long long* p) {
  return __hip_atomic_load(p, __ATOMIC_RELAXED, __HIP_MEMORY_SCOPE_AGENT);
}
__device__ __forceinline__ void astore64(unsigned long long* p, unsigned long long v) {
  __hip_atomic_store(p, v, __ATOMIC_RELAXED, __HIP_MEMORY_SCOPE_AGENT);
}

__device__ __forceinline__ float fdot2u(unsigned a, unsigned b, float c) {
#if __has_builtin(__builtin_amdgcn_fdot2)
  return __builtin_amdgcn_fdot2(__builtin_bit_cast(hf2, a),
                                __builtin_bit_cast(hf2, b), c, false);
#else
  hf2 av = __builtin_bit_cast(hf2, a), bv = __builtin_bit_cast(hf2, b);
  return c + (float)av[0] * (float)bv[0] + (float)av[1] * (float)bv[1];
#endif
}
__device__ __forceinline__ unsigned packh2(float lo, float hi) {
  __half2 h = __floats2half2_rn(lo, hi);
  return __builtin_bit_cast(unsigned, h);
}
__device__ __forceinline__ float f16of(unsigned u, int hi) {
  hf2 v = __builtin_bit_cast(hf2, u);
  return (float)v[hi];
}

// ---------- prep: pack streamed cols 2,3 of each thread's 4-col block --------
// wpk[((r*16+i)*2+c)*512+tid] : uint4 = weight words 4i..4i+3 for col cb+2+c
__global__ __launch_bounds__(512) void k_prep(
    const float* __restrict__ Wh1, const float* __restrict__ Wx2,
    const float* __restrict__ Wh2, uint4* __restrict__ wpk)
{
  const int r = blockIdx.x >> 5;              // role
  const int i = (blockIdx.x >> 1) & 15;       // chunk
  const int c = blockIdx.x & 1;               // streamed col 0/1 -> col 2/3
  const int tid = threadIdx.x;
  const int w = tid >> 6, l = tid & 63, q = l >> 4, lo = l & 15;
  const int col = 4 * (w * 16 + lo) + 2 + c;
  const int k0 = q * 128;
  const float* W = (r == 0) ? Wh1 : ((r == 1) ? Wx2 : Wh2);
  unsigned vv[4];
#pragma unroll
  for (int j = 0; j < 4; ++j) {
    const int k = k0 + 2 * (4 * i + j);
    vv[j] = packh2(W[(size_t)k * HID + col], W[(size_t)(k + 1) * HID + col]);
  }
  wpk[((size_t)(r * 16 + i) * 2 + c) * 512 + tid] = make_uint4(vv[0], vv[1], vv[2], vv[3]);
}

// ---------- xw1[t,b,:] = x[b,t,:] @ Wx1 + b1, packed f16 pairs, all T ----------
__global__ __launch_bounds__(256) void k_xw1(
    const float* __restrict__ x, const float* __restrict__ Wx1,
    const float* __restrict__ b1, unsigned* __restrict__ xw1)   // [T*B][256] words
{
  __shared__ float xst[DIN * 4];
  const int tid  = threadIdx.x;
  const int row0 = blockIdx.x * 4;            // row = t*32 + b
  for (int idx = tid; idx < 4 * DIN; idx += 256) {
    int r = idx >> 7, d = idx & (DIN - 1);
    int row = row0 + r;
    int t = row >> 5, b = row & 31;
    xst[d * 4 + r] = x[((size_t)b * TLEN + t) * DIN + d];
  }
  __syncthreads();
  float acc[4][2];
#pragma unroll
  for (int r = 0; r < 4; ++r) { acc[r][0] = 0.f; acc[r][1] = 0.f; }
  const int j0 = 2 * tid, j1 = 2 * tid + 1;
  for (int d = 0; d < DIN; ++d) {
    float w0 = Wx1[(size_t)d * HID + j0];
    float w1 = Wx1[(size_t)d * HID + j1];
    float4 xv = *reinterpret_cast<const float4*>(&xst[d * 4]);
    acc[0][0] += xv.x * w0; acc[0][1] += xv.x * w1;
    acc[1][0] += xv.y * w0; acc[1][1] += xv.y * w1;
    acc[2][0] += xv.z * w0; acc[2][1] += xv.z * w1;
    acc[3][0] += xv.w * w0; acc[3][1] += xv.w * w1;
  }
  float bb0 = b1[j0], bb1 = b1[j1];
#pragma unroll
  for (int r = 0; r < 4; ++r)
    xw1[(size_t)(row0 + r) * 256 + tid] = packh2(acc[r][0] + bb0, acc[r][1] + bb1);
}

// ---------- persistent 3-role recurrence: 1 batch per WG, chains LDS-local ----
// grid 96 x 512: role = wg/32 (0=A: h1 chain, 1=B: xw2 GEMV, 2=C: h2 chain),
// b = wg%32. Thread (w,l): q=l>>4 (K-quarter), lo=l&15; owns cols cb..cb+3,
// cb=4*(w*16+lo). Weights: cols 0-1 in VGPR (128 words), cols 2-3 streamed
// from L2 (wpk, 8-deep uint4 ring, 4 iters ahead, static slot indices).
// h in LDS, K-regions padded to PADR=68 -> the 4 quarters' broadcast b128
// reads hit disjoint banks. One barrier/step. A->B and B->C links:
// sentinel-flagged full-length u64 buffers (no wrap, no resets, no throttle).
// launch_bounds(512,1): 1 block/CU min -> 256-VGPR cap (r9 spilled at (512,2)).
__global__ __launch_bounds__(512, 1) void k_rnn(
    const unsigned* __restrict__ xw1,            // [T*B][256] f16-pair words
    const float* __restrict__ Wh1, const float* __restrict__ Wx2,
    const float* __restrict__ Wh2, const float* __restrict__ b2,
    const uint4* __restrict__ wpk,               // [3][16][2][512]
    unsigned long long* __restrict__ h1f,        // [T][B][128] u64 (sentinel-init)
    unsigned long long* __restrict__ xw2f,       // [T][B][128] u64 (sentinel-init)
    float* __restrict__ h2fin)                   // [B][H]
{
  const int tid  = threadIdx.x;
  const int wgid = blockIdx.x;
  const int role = wgid >> 5;
  const int b    = wgid & 31;
  const int w  = tid >> 6, l = tid & 63;
  const int q  = l >> 4;
  const int lo = l & 15;
  const int cb = 4 * (w * 16 + lo);            // col base (4 cols per thread)
  const int k0 = q * 128;                      // K-row base for this quarter

  __shared__ __align__(16) unsigned h_s[2][4 * PADR];

  for (int idx = tid; idx < 2 * 4 * PADR; idx += 512)
    ((unsigned*)h_s)[idx] = 0u;

  // ---- cols 0,1 of weights into VGPRs (one-time) ----
  const float* WS = (role == 0) ? Wh1 : ((role == 1) ? Wx2 : Wh2);
  unsigned w0[64], w1[64];
#pragma unroll
  for (int m = 0; m < 64; ++m) {
    const int k = k0 + 2 * m;
    const float *r0 = &WS[(size_t)k * HID + cb], *r1 = &WS[(size_t)(k + 1) * HID + cb];
    w0[m] = packh2(r0[0], r1[0]);
    w1[m] = packh2(r0[1], r1[1]);
  }
  const uint4* wpkR = wpk + (size_t)role * 16 * 2 * 512;
  float4 b2v = make_float4(0.f, 0.f, 0.f, 0.f);
  if (role == 1 && q == 0) b2v = *reinterpret_cast<const float4*>(&b2[cb]);

  const int sgA = cb >> 1;                           // A/C self-stage word base
  const int padA = (sgA >> 6) * PADR + (sgA & 63);
  const int sgB = 2 * tid;                           // B stage (tid<128)
  const int padB = (sgB >> 6) * PADR + (sgB & 63);

  unsigned long long hu = 0;                         // my 4 outputs of prev step
  __syncthreads();

  uint4 wc[8];

  for (int t = 0; t < TLEN; ++t) {
    const int p = t & 1;
    // stream prologue: iters 0-3 (8 uint4), issued first to hide L2 latency
#pragma unroll
    for (int j = 0; j < 8; ++j) wc[j] = wpkR[(size_t)j * 512 + tid];

    unsigned long long xv = 0;                       // A: xw1 word; C: xw2 probe
    const unsigned long long* cprobe = nullptr;

    // ---------------- phase 1 (pre-barrier): stage h + probes ---------------
    if (role == 0) {
      if (q == 0) {
        if (t > 0) *(unsigned long long*)&h_s[p][padA] = hu;   // h1(t-1) -> LDS
        xv = *(const unsigned long long*)&xw1[((size_t)t * BATCH + b) * 256 + (cb >> 1)];
      }
    } else if (role == 1) {
      const unsigned long long* ph = &h1f[((size_t)t * BATCH + b) * 128 + tid];
      if (tid < 128) {
        unsigned long long pv = aload64(ph);
        unsigned it = 0;
        while (pv == SENT64 && ++it < POLL_CAP) pv = aload64(ph);
        if (pv == SENT64) pv = 0;
        *(unsigned long long*)&h_s[p][padB] = pv;              // h1(t) -> LDS
      }
    } else {
      if (q == 0) {
        if (t > 0) *(unsigned long long*)&h_s[p][padA] = hu;   // h2(t-1) -> LDS
        cprobe = &xw2f[((size_t)t * BATCH + b) * 128 + (w * 16 + lo)];
        xv = aload64(cprobe);                                  // early probe
      }
    }

    __syncthreads();   // h stage complete for parity p

    // ---------------- phase 2: publish prev step's output -------------------
    if (role == 0 && q == 0 && t > 0)
      astore64(&h1f[((size_t)(t - 1) * BATCH + b) * 128 + (w * 16 + lo)], hu);
    if (role == 1 && q == 0 && t > 0)
      astore64(&xw2f[((size_t)(t - 1) * BATCH + b) * 128 + (w * 16 + lo)], hu);

    // ---------------- phase 3: dot over this K-quarter, 4 cols --------------
    float a0 = 0.f, a1 = 0.f, a2 = 0.f, a3 = 0.f;
#pragma unroll
    for (int i = 0; i < 16; ++i) {
      uint4 hv = *reinterpret_cast<const uint4*>(&h_s[p][q * PADR + 4 * i]);
      uint4 c2 = wc[(2 * i) & 7];
      uint4 c3 = wc[(2 * i + 1) & 7];
      if (i < 12) {                                  // refill 4 iters ahead
        wc[(2 * i) & 7]     = wpkR[(size_t)((i + 4) * 2 + 0) * 512 + tid];
        wc[(2 * i + 1) & 7] = wpkR[(size_t)((i + 4) * 2 + 1) * 512 + tid];
      }
      a0 = fdot2u(hv.x, w0[4 * i + 0], a0);
      a0 = fdot2u(hv.y, w0[4 * i + 1], a0);
      a0 = fdot2u(hv.z, w0[4 * i + 2], a0);
      a0 = fdot2u(hv.w, w0[4 * i + 3], a0);
      a1 = fdot2u(hv.x, w1[4 * i + 0], a1);
      a1 = fdot2u(hv.y, w1[4 * i + 1], a1);
      a1 = fdot2u(hv.z, w1[4 * i + 2], a1);
      a1 = fdot2u(hv.w, w1[4 * i + 3], a1);
      a2 = fdot2u(hv.x, c2.x, a2);
      a2 = fdot2u(hv.y, c2.y, a2);
      a2 = fdot2u(hv.z, c2.z, a2);
      a2 = fdot2u(hv.w, c2.w, a2);
      a3 = fdot2u(hv.x, c3.x, a3);
      a3 = fdot2u(hv.y, c3.y, a3);
      a3 = fdot2u(hv.z, c3.z, a3);
      a3 = fdot2u(hv.w, c3.w, a3);
    }
    a0 += __shfl_xor(a0, 16); a0 += __shfl_xor(a0, 32);
    a1 += __shfl_xor(a1, 16); a1 += __shfl_xor(a1, 32);
    a2 += __shfl_xor(a2, 16); a2 += __shfl_xor(a2, 32);
    a3 += __shfl_xor(a3, 16); a3 += __shfl_xor(a3, 32);

    // ---------------- phase 4: finalize (q0 lanes own the 4 cols) -----------
    if (q == 0) {
      if (role == 0) {
        unsigned xl = (unsigned)xv, xh = (unsigned)(xv >> 32);
        float h0v = tanhf(a0 + f16of(xl, 0));
        float h1v = tanhf(a1 + f16of(xl, 1));
        float h2v = tanhf(a2 + f16of(xh, 0));
        float h3v = tanhf(a3 + f16of(xh, 1));
        hu = ((unsigned long long)packh2(h2v, h3v) << 32) | packh2(h0v, h1v);
      } else if (role == 1) {
        hu = ((unsigned long long)packh2(a2 + b2v.z, a3 + b2v.w) << 32)
             | packh2(a0 + b2v.x, a1 + b2v.y);
      } else {
        if (xv == SENT64) {
          unsigned it = 0;
          do { xv = aload64(cprobe); } while (xv == SENT64 && ++it < POLL_CAP);
          if (xv == SENT64) xv = 0;
        }
        unsigned xl = (unsigned)xv, xh = (unsigned)(xv >> 32);
        float h0v = tanhf(a0 + f16of(xl, 0));
        float h1v = tanhf(a1 + f16of(xl, 1));
        float h2v = tanhf(a2 + f16of(xh, 0));
        float h3v = tanhf(a3 + f16of(xh, 1));
        hu = ((unsigned long long)packh2(h2v, h3v) << 32) | packh2(h0v, h1v);
        if (t == TLEN - 1)
          *reinterpret_cast<float4*>(&h2fin[(size_t)b * HID + cb]) =
              make_float4(h0v, h1v, h2v, h3v);
      }
    }
  }
  // epilogue: publish the final step's output
  if (role == 0 && q == 0)
    astore64(&h1f[((size_t)(TLEN - 1) * BATCH + b) * 128 + (w * 16 + lo)], hu);
  if (role == 1 && q == 0)
    astore64(&xw2f[((size_t)(TLEN - 1) * BATCH + b) * 128 + (w * 16 + lo)], hu);
}

// ---------- softmax(h2 @ Wo + bo) ----------
__global__ __launch_bounds__(640) void k_head(
    const float* __restrict__ h2, const float* __restrict__ Wo,
    const float* __restrict__ bo, float* __restrict__ out)
{
  __shared__ float lg[16];
  const int b = blockIdx.x;
  const int c = threadIdx.x >> 6;   // wave per class
  const int l = threadIdx.x & 63;
  float p = 0.f;
#pragma unroll
  for (int i = 0; i < 8; ++i) {
    int k = l + 64 * i;
    p += h2[(size_t)b * HID + k] * Wo[(size_t)k * NCLS + c];
  }
  for (int off = 32; off; off >>= 1) p += __shfl_down(p, off);
  if (l == 0) lg[c] = p + bo[c];
  __syncthreads();
  if (threadIdx.x == 0) {
    float m = lg[0];
    for (int i = 1; i < NCLS; ++i) m = fmaxf(m, lg[i]);
    float e[NCLS];
    float s = 0.f;
    for (int i = 0; i < NCLS; ++i) { e[i] = expf(lg[i] - m); s += e[i]; }
    for (int i = 0; i < NCLS; ++i) out[(size_t)b * NCLS + i] = e[i] / s;
  }
}

extern "C" void kernel_launch(void* const* d_in, const int* in_sizes, int n_in,
                              void* d_out, int out_size, void* d_ws, size_t ws_size,
                              hipStream_t stream)
{
  (void)in_sizes; (void)n_in; (void)out_size; (void)ws_size;
  const float* x   = (const float*)d_in[0];
  const float* Wx1 = (const float*)d_in[1];
  const float* Wh1 = (const float*)d_in[2];
  const float* b1  = (const float*)d_in[3];
  const float* Wx2 = (const float*)d_in[4];
  const float* Wh2 = (const float*)d_in[5];
  const float* b2  = (const float*)d_in[6];
  const float* Wo  = (const float*)d_in[7];
  const float* bo  = (const float*)d_in[8];
  float* out = (float*)d_out;

  char* ws = (char*)d_ws;
  size_t o = 0;
  unsigned* xw1 = (unsigned*)(ws + o);              o += (size_t)TLEN * BATCH * 256 * 4;  // 32MB
  unsigned long long* h1f  = (unsigned long long*)(ws + o); o += (size_t)TLEN * BATCH * 128 * 8; // 32MB
  unsigned long long* xw2f = (unsigned long long*)(ws + o); o += (size_t)TLEN * BATCH * 128 * 8; // 32MB
  uint4* wpk = (uint4*)(ws + o);                    o += (size_t)3 * 16 * 2 * 512 * 16;   // 768KB
  float* h2fin = (float*)(ws + o);                  o += (size_t)BATCH * HID * 4;

  // sentinel-init the two link buffers (contiguous, 64MB)
  hipMemsetAsync(h1f, 0xFF, (size_t)2 * TLEN * BATCH * 128 * 8, stream);

  k_prep<<<96, 512, 0, stream>>>(Wh1, Wx2, Wh2, wpk);
  k_xw1<<<TLEN * BATCH / 4, 256, 0, stream>>>(x, Wx1, b1, xw1);
  k_rnn<<<96, 512, 0, stream>>>(xw1, Wh1, Wx2, Wh2, b2, wpk, h1f, xw2f, h2fin);
  k_head<<<BATCH, 640, 0, stream>>>(h2fin, Wo, bo, out);
}

// Round 11
// 3055.849 us; speedup vs baseline: 1.7653x; 1.5100x over previous
//
#include <hip/hip_runtime.h>
#include <hip/hip_fp16.h>
#include <math.h>

#define BATCH 32
#define TLEN  1024
#define DIN   128
#define HID   512
#define NCLS  10
#define SENT64 0xFFFFFFFFFFFFFFFFull
#define POLL_CAP (1u<<17)
#define HPAD 36          // padded region stride (32 words + 4) in u32

typedef _Float16 hf2 __attribute__((ext_vector_type(2)));

__device__ __forceinline__ unsigned long long aload64(const unsigned long long* p) {
  return __hip_atomic_load(p, __ATOMIC_RELAXED, __HIP_MEMORY_SCOPE_AGENT);
}
__device__ __forceinline__ void astore64(unsigned long long* p, unsigned long long v) {
  __hip_atomic_store(p, v, __ATOMIC_RELAXED, __HIP_MEMORY_SCOPE_AGENT);
}

__device__ __forceinline__ float fdot2u(unsigned a, unsigned b, float c) {
#if __has_builtin(__builtin_amdgcn_fdot2)
  return __builtin_amdgcn_fdot2(__builtin_bit_cast(hf2, a),
                                __builtin_bit_cast(hf2, b), c, false);
#else
  hf2 av = __builtin_bit_cast(hf2, a), bv = __builtin_bit_cast(hf2, b);
  return c + (float)av[0] * (float)bv[0] + (float)av[1] * (float)bv[1];
#endif
}
__device__ __forceinline__ unsigned packh2(float lo, float hi) {
  __half2 h = __floats2half2_rn(lo, hi);
  return __builtin_bit_cast(unsigned, h);
}
__device__ __forceinline__ float f16of(unsigned u, int hi) {
  hf2 v = __builtin_bit_cast(hf2, u);
  return (float)v[hi];
}

// ---------- prep: pack all weights into per-thread canonical slots ----------
// Thread (w=tid>>6, l=tid&63): lo=l&7, ks=l>>3; cols cb=4*(w*8+lo)..+3,
// K-rows ks*64..+63. Slot s = c*8+j: col cb+c, rows ks*64+8j..+7 as uint4
// (4 u32, each = f16 pair for rows k,k+1). wpk[(role*32+s)*1024 + tid].
__global__ __launch_bounds__(1024) void k_prep(
    const float* __restrict__ Wh1, const float* __restrict__ Wx2,
    const float* __restrict__ Wh2, uint4* __restrict__ wpk)
{
  const int e = blockIdx.x;
  const int r = e >> 5, slot = e & 31;
  const int c = slot >> 3, j = slot & 7;
  const int tid = threadIdx.x;
  const int w = tid >> 6, l = tid & 63, lo = l & 7, ks = l >> 3;
  const int col = 4 * (w * 8 + lo) + c;
  const int k0 = ks * 64 + 8 * j;
  const float* W = (r == 0) ? Wh1 : ((r == 1) ? Wx2 : Wh2);
  unsigned vv[4];
#pragma unroll
  for (int m = 0; m < 4; ++m) {
    const int k = k0 + 2 * m;
    vv[m] = packh2(W[(size_t)k * HID + col], W[(size_t)(k + 1) * HID + col]);
  }
  wpk[((size_t)(r * 32 + slot)) * 1024 + tid] = make_uint4(vv[0], vv[1], vv[2], vv[3]);
}

// ---------- xw1[t,b,:] = x[b,t,:] @ Wx1 + b1, packed f16 pairs, all T ----------
__global__ __launch_bounds__(256) void k_xw1(
    const float* __restrict__ x, const float* __restrict__ Wx1,
    const float* __restrict__ b1, unsigned* __restrict__ xw1)   // [T*B][256] words
{
  __shared__ float xst[DIN * 4];
  const int tid  = threadIdx.x;
  const int row0 = blockIdx.x * 4;            // row = t*32 + b
  for (int idx = tid; idx < 4 * DIN; idx += 256) {
    int r = idx >> 7, d = idx & (DIN - 1);
    int row = row0 + r;
    int t = row >> 5, b = row & 31;
    xst[d * 4 + r] = x[((size_t)b * TLEN + t) * DIN + d];
  }
  __syncthreads();
  float acc[4][2];
#pragma unroll
  for (int r = 0; r < 4; ++r) { acc[r][0] = 0.f; acc[r][1] = 0.f; }
  const int j0 = 2 * tid, j1 = 2 * tid + 1;
  for (int d = 0; d < DIN; ++d) {
    float w0 = Wx1[(size_t)d * HID + j0];
    float w1 = Wx1[(size_t)d * HID + j1];
    float4 xv = *reinterpret_cast<const float4*>(&xst[d * 4]);
    acc[0][0] += xv.x * w0; acc[0][1] += xv.x * w1;
    acc[1][0] += xv.y * w0; acc[1][1] += xv.y * w1;
    acc[2][0] += xv.z * w0; acc[2][1] += xv.z * w1;
    acc[3][0] += xv.w * w0; acc[3][1] += xv.w * w1;
  }
  float bb0 = b1[j0], bb1 = b1[j1];
#pragma unroll
  for (int r = 0; r < 4; ++r)
    xw1[(size_t)(row0 + r) * 256 + tid] = packh2(acc[r][0] + bb0, acc[r][1] + bb1);
}

// ---------- persistent 3-role recurrence: 1024 threads, 1 batch per WG -------
// grid 96 x 1024: role = wg/32 (0=A: h1 chain, 1=B: xw2 GEMV, 2=C: h2 chain),
// b = wg%32. Thread: 4 cols x 64 K-rows = 32 weight-uint4, split 16 VGPR /
// 9 LDS (147KB, [slot][tid] conflict-free) / 7 streamed from L2 (issued at
// end of each step's dot, consumed next step -> full-step latency hiding).
// h in LDS, 8 regions padded to HPAD=36 -> 8 K-eighths hit disjoint bank
// quads. Reduction: 3x shfl_xor. One barrier/step. A->B, B->C links:
// sentinel-flagged full-length u64 buffers. 1024-thread block => compiler is
// FORCED to <=128 VGPR (16 waves fill the CU) and demand (~122) fits: no
// spill (r9/r10 lesson: 512-thread blocks were silently budget-capped at 128).
__global__ __launch_bounds__(1024, 4) void k_rnn(
    const unsigned* __restrict__ xw1,            // [T*B][256] f16-pair words
    const float* __restrict__ b2,
    const uint4* __restrict__ wpk,               // [3][32][1024]
    unsigned long long* __restrict__ h1f,        // [T][B][128] u64 (sentinel-init)
    unsigned long long* __restrict__ xw2f,       // [T][B][128] u64 (sentinel-init)
    float* __restrict__ h2fin)                   // [B][H]
{
  const int tid  = threadIdx.x;
  const int wgid = blockIdx.x;
  const int role = wgid >> 5;
  const int b    = wgid & 31;
  const int w  = tid >> 6, l = tid & 63;
  const int lo = l & 7;
  const int ks = l >> 3;                       // K-eighth (64 rows)
  const int u  = w * 8 + lo;                   // col-group 0..127
  const int cb = 4 * u;                        // col base (4 cols per thread)

  __shared__ __align__(16) uint4 wl_s[9][1024];       // 147456 B
  __shared__ __align__(16) unsigned h_s[2][8 * HPAD]; // 2304 B

  if (tid < 2 * 8 * HPAD) ((unsigned*)h_s)[tid] = 0u;

  // ---- one-time: VGPR weights (slots 0-15), LDS weights (slots 16-24) ----
  const uint4* wp = wpk + (size_t)(role * 32) * 1024 + tid;
  uint4 wa[16];
#pragma unroll
  for (int s = 0; s < 16; ++s) wa[s] = wp[(size_t)s * 1024];
#pragma unroll
  for (int s = 0; s < 9; ++s) wl_s[s][tid] = wp[(size_t)(16 + s) * 1024];
  const uint4* wsp = wp + (size_t)25 * 1024;   // stream slots 25-31
  uint4 wsr[7];
#pragma unroll
  for (int i = 0; i < 7; ++i) wsr[i] = wsp[(size_t)i * 1024];

  float4 b2v = make_float4(0.f, 0.f, 0.f, 0.f);
  if (role == 1 && ks == 0) b2v = *reinterpret_cast<const float4*>(&b2[cb]);

  // staged u64 address for my output word pair (W = cb>>1 = 2u, even)
  const int padO = (u >> 4) * HPAD + 2 * (u & 15);

  unsigned long long hu = 0;                   // my 4 outputs of prev step
  __syncthreads();                             // wl_s + h_s zero complete

  for (int t = 0; t < TLEN; ++t) {
    const int p = t & 1;
    unsigned long long xv = 0;                 // A: xw1 word; C: xw2 probe
    const unsigned long long* cprobe = nullptr;

    // ---------------- phase 1 (pre-barrier): stage h + probes ---------------
    if (role == 0) {
      if (ks == 0) {
        if (t > 0) *(unsigned long long*)&h_s[p][padO] = hu;   // h1(t-1) -> LDS
        xv = *(const unsigned long long*)&xw1[(size_t)t * 8192 + b * 256 + 2 * u];
      }
    } else if (role == 1) {
      if (tid < 128) {
        const unsigned long long* ph = &h1f[((size_t)t * BATCH + b) * 128 + tid];
        unsigned long long pv = aload64(ph);
        unsigned it = 0;
        while (pv == SENT64 && ++it < POLL_CAP) pv = aload64(ph);
        if (pv == SENT64) pv = 0;
        *(unsigned long long*)&h_s[p][(tid >> 4) * HPAD + 2 * (tid & 15)] = pv;
      }
    } else {
      if (ks == 0) {
        if (t > 0) *(unsigned long long*)&h_s[p][padO] = hu;   // h2(t-1) -> LDS
        cprobe = &xw2f[((size_t)t * BATCH + b) * 128 + u];
        xv = aload64(cprobe);                                  // early probe
      }
    }

    __syncthreads();   // h_s[p] ready

    // ---------------- phase 2: publish prev step's output -------------------
    if (role == 0 && ks == 0 && t > 0)
      astore64(&h1f[((size_t)(t - 1) * BATCH + b) * 128 + u], hu);
    if (role == 1 && ks == 0 && t > 0)
      astore64(&xw2f[((size_t)(t - 1) * BATCH + b) * 128 + u], hu);

    // ---------------- phase 3: dot over this K-eighth, 4 cols ---------------
    float a0 = 0.f, a1 = 0.f, a2 = 0.f, a3 = 0.f;
#pragma unroll
    for (int j = 0; j < 8; ++j) {
      uint4 hv = *reinterpret_cast<const uint4*>(&h_s[p][ks * HPAD + 4 * j]);
      uint4 c0 = wa[j];
      uint4 c1 = wa[8 + j];
      uint4 c2 = wl_s[j][tid];
      uint4 c3 = (j == 0) ? wl_s[8][tid] : wsr[j - 1];   // static after unroll
      a0 = fdot2u(hv.x, c0.x, a0);
      a0 = fdot2u(hv.y, c0.y, a0);
      a0 = fdot2u(hv.z, c0.z, a0);
      a0 = fdot2u(hv.w, c0.w, a0);
      a1 = fdot2u(hv.x, c1.x, a1);
      a1 = fdot2u(hv.y, c1.y, a1);
      a1 = fdot2u(hv.z, c1.z, a1);
      a1 = fdot2u(hv.w, c1.w, a1);
      a2 = fdot2u(hv.x, c2.x, a2);
      a2 = fdot2u(hv.y, c2.y, a2);
      a2 = fdot2u(hv.z, c2.z, a2);
      a2 = fdot2u(hv.w, c2.w, a2);
      a3 = fdot2u(hv.x, c3.x, a3);
      a3 = fdot2u(hv.y, c3.y, a3);
      a3 = fdot2u(hv.z, c3.z, a3);
      a3 = fdot2u(hv.w, c3.w, a3);
    }
    // refill stream for NEXT step (full step of latency to hide)
#pragma unroll
    for (int i = 0; i < 7; ++i) wsr[i] = wsp[(size_t)i * 1024];

    // reduce across the 8 K-eighths
    a0 += __shfl_xor(a0, 8); a0 += __shfl_xor(a0, 16); a0 += __shfl_xor(a0, 32);
    a1 += __shfl_xor(a1, 8); a1 += __shfl_xor(a1, 16); a1 += __shfl_xor(a1, 32);
    a2 += __shfl_xor(a2, 8); a2 += __shfl_xor(a2, 16); a2 += __shfl_xor(a2, 32);
    a3 += __shfl_xor(a3, 8); a3 += __shfl_xor(a3, 16); a3 += __shfl_xor(a3, 32);

    // ---------------- phase 4: finalize (ks==0 lanes own the 4 cols) --------
    if (ks == 0) {
      if (role == 0) {
        unsigned xl = (unsigned)xv, xh = (unsigned)(xv >> 32);
        float h0v = tanhf(a0 + f16of(xl, 0));
        float h1v = tanhf(a1 + f16of(xl, 1));
        float h2v = tanhf(a2 + f16of(xh, 0));
        float h3v = tanhf(a3 + f16of(xh, 1));
        hu = ((unsigned long long)packh2(h2v, h3v) << 32) | packh2(h0v, h1v);
      } else if (role == 1) {
        hu = ((unsigned long long)packh2(a2 + b2v.z, a3 + b2v.w) << 32)
             | packh2(a0 + b2v.x, a1 + b2v.y);
      } else {
        if (xv == SENT64) {
          unsigned it = 0;
          do { xv = aload64(cprobe); } while (xv == SENT64 && ++it < POLL_CAP);
          if (xv == SENT64) xv = 0;
        }
        unsigned xl = (unsigned)xv, xh = (unsigned)(xv >> 32);
        float h0v = tanhf(a0 + f16of(xl, 0));
        float h1v = tanhf(a1 + f16of(xl, 1));
        float h2v = tanhf(a2 + f16of(xh, 0));
        float h3v = tanhf(a3 + f16of(xh, 1));
        hu = ((unsigned long long)packh2(h2v, h3v) << 32) | packh2(h0v, h1v);
        if (t == TLEN - 1)
          *reinterpret_cast<float4*>(&h2fin[(size_t)b * HID + cb]) =
              make_float4(h0v, h1v, h2v, h3v);
      }
    }
  }
  // epilogue: publish the final step's output
  if (role == 0 && ks == 0)
    astore64(&h1f[((size_t)(TLEN - 1) * BATCH + b) * 128 + u], hu);
  if (role == 1 && ks == 0)
    astore64(&xw2f[((size_t)(TLEN - 1) * BATCH + b) * 128 + u], hu);
}

// ---------- softmax(h2 @ Wo + bo) ----------
__global__ __launch_bounds__(640) void k_head(
    const float* __restrict__ h2, const float* __restrict__ Wo,
    const float* __restrict__ bo, float* __restrict__ out)
{
  __shared__ float lg[16];
  const int b = blockIdx.x;
  const int c = threadIdx.x >> 6;   // wave per class
  const int l = threadIdx.x & 63;
  float p = 0.f;
#pragma unroll
  for (int i = 0; i < 8; ++i) {
    int k = l + 64 * i;
    p += h2[(size_t)b * HID + k] * Wo[(size_t)k * NCLS + c];
  }
  for (int off = 32; off; off >>= 1) p += __shfl_down(p, off);
  if (l == 0) lg[c] = p + bo[c];
  __syncthreads();
  if (threadIdx.x == 0) {
    float m = lg[0];
    for (int i = 1; i < NCLS; ++i) m = fmaxf(m, lg[i]);
    float e[NCLS];
    float s = 0.f;
    for (int i = 0; i < NCLS; ++i) { e[i] = expf(lg[i] - m); s += e[i]; }
    for (int i = 0; i < NCLS; ++i) out[(size_t)b * NCLS + i] = e[i] / s;
  }
}

extern "C" void kernel_launch(void* const* d_in, const int* in_sizes, int n_in,
                              void* d_out, int out_size, void* d_ws, size_t ws_size,
                              hipStream_t stream)
{
  (void)in_sizes; (void)n_in; (void)out_size; (void)ws_size;
  const float* x   = (const float*)d_in[0];
  const float* Wx1 = (const float*)d_in[1];
  const float* Wh1 = (const float*)d_in[2];
  const float* b1  = (const float*)d_in[3];
  const float* Wx2 = (const float*)d_in[4];
  const float* Wh2 = (const float*)d_in[5];
  const float* b2  = (const float*)d_in[6];
  const float* Wo  = (const float*)d_in[7];
  const float* bo  = (const float*)d_in[8];
  float* out = (float*)d_out;

  char* ws = (char*)d_ws;
  size_t o = 0;
  unsigned* xw1 = (unsigned*)(ws + o);              o += (size_t)TLEN * BATCH * 256 * 4;  // 32MB
  unsigned long long* h1f  = (unsigned long long*)(ws + o); o += (size_t)TLEN * BATCH * 128 * 8; // 32MB
  unsigned long long* xw2f = (unsigned long long*)(ws + o); o += (size_t)TLEN * BATCH * 128 * 8; // 32MB
  uint4* wpk = (uint4*)(ws + o);                    o += (size_t)3 * 32 * 1024 * 16;      // 1.5MB
  float* h2fin = (float*)(ws + o);                  o += (size_t)BATCH * HID * 4;

  // sentinel-init the two link buffers (contiguous, 64MB)
  hipMemsetAsync(h1f, 0xFF, (size_t)2 * TLEN * BATCH * 128 * 8, stream);

  k_prep<<<96, 1024, 0, stream>>>(Wh1, Wx2, Wh2, wpk);
  k_xw1<<<TLEN * BATCH / 4, 256, 0, stream>>>(x, Wx1, b1, xw1);
  k_rnn<<<96, 1024, 0, stream>>>(xw1, b2, wpk, h1f, xw2f, h2fin);
  k_head<<<BATCH, 640, 0, stream>>>(h2fin, Wo, bo, out);
}

// Round 12
// 2452.740 us; speedup vs baseline: 2.1993x; 1.2459x over previous
//
#include <hip/hip_runtime.h>
#include <hip/hip_fp16.h>
#include <math.h>

#define BATCH 32
#define TLEN  1024
#define DIN   128
#define HID   512
#define NCLS  10
#define SENT64 0xFFFFFFFFFFFFFFFFull
#define POLL_CAP (1u<<17)
#define PADR 68          // padded K-region stride in u32 words (64 + 4)

typedef _Float16 hf2 __attribute__((ext_vector_type(2)));

__device__ __forceinline__ unsigned long long aload64(const unsigned long long* p) {
  return __hip_atomic_load(p, __ATOMIC_RELAXED, __HIP_MEMORY_SCOPE_AGENT);
}
__device__ __forceinline__ void astore64(unsigned long long* p, unsigned long long v) {
  __hip_atomic_store(p, v, __ATOMIC_RELAXED, __HIP_MEMORY_SCOPE_AGENT);
}

__device__ __forceinline__ float fdot2u(unsigned a, unsigned b, float c) {
#if __has_builtin(__builtin_amdgcn_fdot2)
  return __builtin_amdgcn_fdot2(__builtin_bit_cast(hf2, a),
                                __builtin_bit_cast(hf2, b), c, false);
#else
  hf2 av = __builtin_bit_cast(hf2, a), bv = __builtin_bit_cast(hf2, b);
  return c + (float)av[0] * (float)bv[0] + (float)av[1] * (float)bv[1];
#endif
}
__device__ __forceinline__ unsigned packh2(float lo, float hi) {
  __half2 h = __floats2half2_rn(lo, hi);
  return __builtin_bit_cast(unsigned, h);
}
__device__ __forceinline__ float f16of(unsigned u, int hi) {
  hf2 v = __builtin_bit_cast(hf2, u);
  return (float)v[hi];
}

// ---------- prep: pack col3 of each thread's 4-col block into [slot][tid] ----
// wcol3[(r*16+s)*512+tid] : uint4 = col cb+3, h-word-group s (rows 8s..8s+7
// of the thread's K-quarter), matching the dot loop's h word groups.
__global__ __launch_bounds__(512) void k_prep(
    const float* __restrict__ Wh1, const float* __restrict__ Wx2,
    const float* __restrict__ Wh2, uint4* __restrict__ wcol3)
{
  const int r = blockIdx.x >> 4;
  const int s = blockIdx.x & 15;
  const int tid = threadIdx.x;
  const int w = tid >> 6, l = tid & 63, q = l >> 4, lo = l & 15;
  const int col3 = 4 * (w * 16 + lo) + 3;
  const int k0 = q * 128;
  const float* W = (r == 0) ? Wh1 : ((r == 1) ? Wx2 : Wh2);
  unsigned vv[4];
#pragma unroll
  for (int j = 0; j < 4; ++j) {
    const int k = k0 + 2 * (4 * s + j);
    vv[j] = packh2(W[(size_t)k * HID + col3], W[(size_t)(k + 1) * HID + col3]);
  }
  wcol3[((size_t)r * 16 + s) * 512 + tid] = make_uint4(vv[0], vv[1], vv[2], vv[3]);
}

// ---------- xw1[t,b,:] = x[b,t,:] @ Wx1 + b1, packed f16 pairs, all T ----------
__global__ __launch_bounds__(256) void k_xw1(
    const float* __restrict__ x, const float* __restrict__ Wx1,
    const float* __restrict__ b1, unsigned* __restrict__ xw1)   // [T*B][256] words
{
  __shared__ float xst[DIN * 4];
  const int tid  = threadIdx.x;
  const int row0 = blockIdx.x * 4;            // row = t*32 + b
  for (int idx = tid; idx < 4 * DIN; idx += 256) {
    int r = idx >> 7, d = idx & (DIN - 1);
    int row = row0 + r;
    int t = row >> 5, b = row & 31;
    xst[d * 4 + r] = x[((size_t)b * TLEN + t) * DIN + d];
  }
  __syncthreads();
  float acc[4][2];
#pragma unroll
  for (int r = 0; r < 4; ++r) { acc[r][0] = 0.f; acc[r][1] = 0.f; }
  const int j0 = 2 * tid, j1 = 2 * tid + 1;
  for (int d = 0; d < DIN; ++d) {
    float w0 = Wx1[(size_t)d * HID + j0];
    float w1 = Wx1[(size_t)d * HID + j1];
    float4 xv = *reinterpret_cast<const float4*>(&xst[d * 4]);
    acc[0][0] += xv.x * w0; acc[0][1] += xv.x * w1;
    acc[1][0] += xv.y * w0; acc[1][1] += xv.y * w1;
    acc[2][0] += xv.z * w0; acc[2][1] += xv.z * w1;
    acc[3][0] += xv.w * w0; acc[3][1] += xv.w * w1;
  }
  float bb0 = b1[j0], bb1 = b1[j1];
#pragma unroll
  for (int r = 0; r < 4; ++r)
    xw1[(size_t)(row0 + r) * 256 + tid] = packh2(acc[r][0] + bb0, acc[r][1] + bb1);
}

// ---------- persistent 3-role recurrence: 1 batch per WG, chains LDS-local ----
// grid 96 x 512: role = wg/32 (0=A: h1 chain, 1=B: xw2 GEMV, 2=C: h2 chain),
// b = wg%32. Thread (w,l): q=l>>4 (K-quarter), lo=l&15; owns cols cb..cb+3.
// FULL weight matrix CU-resident: cols 0-2 in VGPR (192 words, rotated init),
// col 3 in LDS wl_s[16][512] (128KB, one-time fill; slot (i+q)&15 matches the
// rotated h word group). ZERO steady-state L2 weight traffic (r10/r11 were
// L2-BW-bound on re-streaming). amdgpu_waves_per_eu(2,2): 8 waves = exactly
// 2/EU -> 256-VGPR cap, overriding the allocator's 128-reg heuristic that
// silently spilled r5/r9/r10/r11. h in LDS, K-regions padded to PADR=68;
// one barrier/step; A->B, B->C links = sentinel-flagged full-length buffers.
__global__ __launch_bounds__(512)
__attribute__((amdgpu_waves_per_eu(2, 2)))
void k_rnn(
    const unsigned* __restrict__ xw1,            // [T*B][256] f16-pair words
    const float* __restrict__ Wh1, const float* __restrict__ Wx2,
    const float* __restrict__ Wh2, const float* __restrict__ b2,
    const uint4* __restrict__ wcol3,             // [3][16][512]
    unsigned long long* __restrict__ h1f,        // [T][B][128] u64 (sentinel-init)
    unsigned long long* __restrict__ xw2f,       // [T][B][128] u64 (sentinel-init)
    float* __restrict__ h2fin)                   // [B][H]
{
  const int tid  = threadIdx.x;
  const int wgid = blockIdx.x;
  const int role = wgid >> 5;
  const int b    = wgid & 31;
  const int w  = tid >> 6, l = tid & 63;
  const int q  = l >> 4;
  const int lo = l & 15;
  const int cb = 4 * (w * 16 + lo);            // col base (4 cols per thread)
  const int k0 = q * 128;                      // K-row base for this quarter

  __shared__ __align__(16) uint4 wl_s[16][512];       // 131072 B (col-3 weights)
  __shared__ __align__(16) unsigned h_s[2][4 * PADR]; // 2176 B

  for (int idx = tid; idx < 2 * 4 * PADR; idx += 512)
    ((unsigned*)h_s)[idx] = 0u;

  // ---- one-time: col-3 weights into LDS ----
  {
    const uint4* wp = wcol3 + (size_t)role * 16 * 512 + tid;
#pragma unroll
    for (int s = 0; s < 16; ++s) wl_s[s][tid] = wp[(size_t)s * 512];
  }
  // ---- one-time: cols 0-2 into VGPRs, rotated load order (static indices) ----
  const float* WS = (role == 0) ? Wh1 : ((role == 1) ? Wx2 : Wh2);
  unsigned w0[64], w1[64], w2[64];
#pragma unroll
  for (int i = 0; i < 16; ++i) {
    const int rr = 4 * ((i + q) & 15);         // rotated word offset in quarter
#pragma unroll
    for (int j = 0; j < 4; ++j) {
      const int k = k0 + 2 * (rr + j);
      const float *r0 = &WS[(size_t)k * HID + cb], *r1 = &WS[(size_t)(k + 1) * HID + cb];
      w0[4 * i + j] = packh2(r0[0], r1[0]);
      w1[4 * i + j] = packh2(r0[1], r1[1]);
      w2[4 * i + j] = packh2(r0[2], r1[2]);
    }
  }
  float4 b2v = make_float4(0.f, 0.f, 0.f, 0.f);
  if (role == 1 && q == 0) b2v = *reinterpret_cast<const float4*>(&b2[cb]);

  const int sgA = cb >> 1;                           // A/C self-stage word base
  const int padA = (sgA >> 6) * PADR + (sgA & 63);
  const int sgB = 2 * tid;                           // B stage (tid<128)
  const int padB = (sgB >> 6) * PADR + (sgB & 63);

  unsigned long long hu = 0;                         // my 4 outputs of prev step
  __syncthreads();                                   // wl_s + h_s zero complete

  for (int t = 0; t < TLEN; ++t) {
    const int p = t & 1;
    unsigned long long xv = 0;                       // A: xw1 word; C: xw2 probe
    const unsigned long long* cprobe = nullptr;

    // ---------------- phase 1 (pre-barrier): stage h + probes ---------------
    if (role == 0) {
      if (q == 0) {
        if (t > 0) *(unsigned long long*)&h_s[p][padA] = hu;   // h1(t-1) -> LDS
        xv = *(const unsigned long long*)&xw1[((size_t)t * BATCH + b) * 256 + (cb >> 1)];
      }
    } else if (role == 1) {
      if (tid < 128) {
        const unsigned long long* ph = &h1f[((size_t)t * BATCH + b) * 128 + tid];
        unsigned long long pv = aload64(ph);
        unsigned it = 0;
        while (pv == SENT64 && ++it < POLL_CAP) pv = aload64(ph);
        if (pv == SENT64) pv = 0;
        *(unsigned long long*)&h_s[p][padB] = pv;              // h1(t) -> LDS
      }
    } else {
      if (q == 0) {
        if (t > 0) *(unsigned long long*)&h_s[p][padA] = hu;   // h2(t-1) -> LDS
        cprobe = &xw2f[((size_t)t * BATCH + b) * 128 + (w * 16 + lo)];
        xv = aload64(cprobe);                                  // early probe
      }
    }

    __syncthreads();   // h_s[p] ready

    // ---------------- phase 2: publish prev step's output -------------------
    if (role == 0 && q == 0 && t > 0)
      astore64(&h1f[((size_t)(t - 1) * BATCH + b) * 128 + (w * 16 + lo)], hu);
    if (role == 1 && q == 0 && t > 0)
      astore64(&xw2f[((size_t)(t - 1) * BATCH + b) * 128 + (w * 16 + lo)], hu);

    // ---------------- phase 3: dot over this K-quarter, 4 cols --------------
    float a0 = 0.f, a1 = 0.f, a2 = 0.f, a3 = 0.f;
#pragma unroll
    for (int i = 0; i < 16; ++i) {
      const int sidx = (i + q) & 15;               // rotated slot / word group
      uint4 hv = *reinterpret_cast<const uint4*>(&h_s[p][q * PADR + 4 * sidx]);
      uint4 c3 = wl_s[sidx][tid];
      a0 = fdot2u(hv.x, w0[4 * i + 0], a0);
      a0 = fdot2u(hv.y, w0[4 * i + 1], a0);
      a0 = fdot2u(hv.z, w0[4 * i + 2], a0);
      a0 = fdot2u(hv.w, w0[4 * i + 3], a0);
      a1 = fdot2u(hv.x, w1[4 * i + 0], a1);
      a1 = fdot2u(hv.y, w1[4 * i + 1], a1);
      a1 = fdot2u(hv.z, w1[4 * i + 2], a1);
      a1 = fdot2u(hv.w, w1[4 * i + 3], a1);
      a2 = fdot2u(hv.x, w2[4 * i + 0], a2);
      a2 = fdot2u(hv.y, w2[4 * i + 1], a2);
      a2 = fdot2u(hv.z, w2[4 * i + 2], a2);
      a2 = fdot2u(hv.w, w2[4 * i + 3], a2);
      a3 = fdot2u(hv.x, c3.x, a3);
      a3 = fdot2u(hv.y, c3.y, a3);
      a3 = fdot2u(hv.z, c3.z, a3);
      a3 = fdot2u(hv.w, c3.w, a3);
    }
    a0 += __shfl_xor(a0, 16); a0 += __shfl_xor(a0, 32);
    a1 += __shfl_xor(a1, 16); a1 += __shfl_xor(a1, 32);
    a2 += __shfl_xor(a2, 16); a2 += __shfl_xor(a2, 32);
    a3 += __shfl_xor(a3, 16); a3 += __shfl_xor(a3, 32);

    // ---------------- phase 4: finalize (q0 lanes own the 4 cols) -----------
    if (q == 0) {
      if (role == 0) {
        unsigned xl = (unsigned)xv, xh = (unsigned)(xv >> 32);
        float h0v = tanhf(a0 + f16of(xl, 0));
        float h1v = tanhf(a1 + f16of(xl, 1));
        float h2v = tanhf(a2 + f16of(xh, 0));
        float h3v = tanhf(a3 + f16of(xh, 1));
        hu = ((unsigned long long)packh2(h2v, h3v) << 32) | packh2(h0v, h1v);
      } else if (role == 1) {
        hu = ((unsigned long long)packh2(a2 + b2v.z, a3 + b2v.w) << 32)
             | packh2(a0 + b2v.x, a1 + b2v.y);
      } else {
        if (xv == SENT64) {
          unsigned it = 0;
          do { xv = aload64(cprobe); } while (xv == SENT64 && ++it < POLL_CAP);
          if (xv == SENT64) xv = 0;
        }
        unsigned xl = (unsigned)xv, xh = (unsigned)(xv >> 32);
        float h0v = tanhf(a0 + f16of(xl, 0));
        float h1v = tanhf(a1 + f16of(xl, 1));
        float h2v = tanhf(a2 + f16of(xh, 0));
        float h3v = tanhf(a3 + f16of(xh, 1));
        hu = ((unsigned long long)packh2(h2v, h3v) << 32) | packh2(h0v, h1v);
        if (t == TLEN - 1)
          *reinterpret_cast<float4*>(&h2fin[(size_t)b * HID + cb]) =
              make_float4(h0v, h1v, h2v, h3v);
      }
    }
  }
  // epilogue: publish the final step's output
  if (role == 0 && q == 0)
    astore64(&h1f[((size_t)(TLEN - 1) * BATCH + b) * 128 + (w * 16 + lo)], hu);
  if (role == 1 && q == 0)
    astore64(&xw2f[((size_t)(TLEN - 1) * BATCH + b) * 128 + (w * 16 + lo)], hu);
}

// ---------- softmax(h2 @ Wo + bo) ----------
__global__ __launch_bounds__(640) void k_head(
    const float* __restrict__ h2, const float* __restrict__ Wo,
    const float* __restrict__ bo, float* __restrict__ out)
{
  __shared__ float lg[16];
  const int b = blockIdx.x;
  const int c = threadIdx.x >> 6;   // wave per class
  const int l = threadIdx.x & 63;
  float p = 0.f;
#pragma unroll
  for (int i = 0; i < 8; ++i) {
    int k = l + 64 * i;
    p += h2[(size_t)b * HID + k] * Wo[(size_t)k * NCLS + c];
  }
  for (int off = 32; off; off >>= 1) p += __shfl_down(p, off);
  if (l == 0) lg[c] = p + bo[c];
  __syncthreads();
  if (threadIdx.x == 0) {
    float m = lg[0];
    for (int i = 1; i < NCLS; ++i) m = fmaxf(m, lg[i]);
    float e[NCLS];
    float s = 0.f;
    for (int i = 0; i < NCLS; ++i) { e[i] = expf(lg[i] - m); s += e[i]; }
    for (int i = 0; i < NCLS; ++i) out[(size_t)b * NCLS + i] = e[i] / s;
  }
}

extern "C" void kernel_launch(void* const* d_in, const int* in_sizes, int n_in,
                              void* d_out, int out_size, void* d_ws, size_t ws_size,
                              hipStream_t stream)
{
  (void)in_sizes; (void)n_in; (void)out_size; (void)ws_size;
  const float* x   = (const float*)d_in[0];
  const float* Wx1 = (const float*)d_in[1];
  const float* Wh1 = (const float*)d_in[2];
  const float* b1  = (const float*)d_in[3];
  const float* Wx2 = (const float*)d_in[4];
  const float* Wh2 = (const float*)d_in[5];
  const float* b2  = (const float*)d_in[6];
  const float* Wo  = (const float*)d_in[7];
  const float* bo  = (const float*)d_in[8];
  float* out = (float*)d_out;

  char* ws = (char*)d_ws;
  size_t o = 0;
  unsigned* xw1 = (unsigned*)(ws + o);              o += (size_t)TLEN * BATCH * 256 * 4;  // 32MB
  unsigned long long* h1f  = (unsigned long long*)(ws + o); o += (size_t)TLEN * BATCH * 128 * 8; // 32MB
  unsigned long long* xw2f = (unsigned long long*)(ws + o); o += (size_t)TLEN * BATCH * 128 * 8; // 32MB
  uint4* wcol3 = (uint4*)(ws + o);                  o += (size_t)3 * 16 * 512 * 16;       // 384KB
  float* h2fin = (float*)(ws + o);                  o += (size_t)BATCH * HID * 4;

  // sentinel-init the two link buffers (contiguous, 64MB)
  hipMemsetAsync(h1f, 0xFF, (size_t)2 * TLEN * BATCH * 128 * 8, stream);

  k_prep<<<48, 512, 0, stream>>>(Wh1, Wx2, Wh2, wcol3);
  k_xw1<<<TLEN * BATCH / 4, 256, 0, stream>>>(x, Wx1, b1, xw1);
  k_rnn<<<96, 512, 0, stream>>>(xw1, Wh1, Wx2, Wh2, b2, wcol3, h1f, xw2f, h2fin);
  k_head<<<BATCH, 640, 0, stream>>>(h2fin, Wo, bo, out);
}